// Round 1
// baseline (45.702 us; speedup 1.0000x reference)
//
#include <hip/hip_runtime.h>

// InfoNCE loss: only the gathered 64 columns of sim are ever used, so we
// compute exactly those. One wave (64 lanes) per batch row; lane c owns
// candidate c (lane 0 = positive index, lanes 1..63 = negatives).

constexpr int BATCH = 2048;
constexpr int DIM   = 128;
constexpr int N_NEG = 63;
constexpr float TEMP_INV = 1.0f / 0.07f;
constexpr float EPSF = 1e-12f;

__global__ __launch_bounds__(256) void infonce_kernel(
    const float* __restrict__ q,    // [BATCH][DIM]
    const float* __restrict__ r,    // [VOCAB][DIM]
    const int*   __restrict__ pos,  // [BATCH]
    const int*   __restrict__ neg,  // [BATCH][N_NEG]
    float* __restrict__ out)        // [1]
{
    __shared__ float qs[4][DIM];

    const int wave = threadIdx.x >> 6;
    const int lane = threadIdx.x & 63;
    const int b    = blockIdx.x * 4 + wave;   // grid sized exactly: b < BATCH

    // --- stage q row into LDS; compute ||q||^2 via wave reduce ---
    float2 q2 = *reinterpret_cast<const float2*>(q + (size_t)b * DIM + lane * 2);
    qs[wave][lane * 2]     = q2.x;
    qs[wave][lane * 2 + 1] = q2.y;
    float qn = q2.x * q2.x + q2.y * q2.y;
    #pragma unroll
    for (int s = 32; s >= 1; s >>= 1) qn += __shfl_xor(qn, s, 64);

    __syncthreads();   // all 256 threads reach this (grid exact, no divergence)

    // --- lane c gathers candidate row, computes dot & ||r||^2 ---
    int idx = (lane == 0) ? pos[b] : neg[(size_t)b * N_NEG + (lane - 1)];
    const float4* rrow = reinterpret_cast<const float4*>(r + (size_t)idx * DIM);
    const float4* qrow = reinterpret_cast<const float4*>(qs[wave]);

    float dot = 0.0f, rn = 0.0f;
    #pragma unroll
    for (int j = 0; j < DIM / 4; ++j) {
        float4 rv = rrow[j];
        float4 qv = qrow[j];            // same addr across lanes -> LDS broadcast
        dot += qv.x * rv.x + qv.y * rv.y + qv.z * rv.z + qv.w * rv.w;
        rn  += rv.x * rv.x + rv.y * rv.y + rv.z * rv.z + rv.w * rv.w;
    }

    float qnorm = fmaxf(sqrtf(qn), EPSF);
    float rnorm = fmaxf(sqrtf(rn), EPSF);
    float s = dot / (qnorm * rnorm) * TEMP_INV;   // sim value for candidate `lane`

    // --- 64-way logsumexp across the wave ---
    float m = s;
    #pragma unroll
    for (int d = 32; d >= 1; d >>= 1) m = fmaxf(m, __shfl_xor(m, d, 64));
    float e = __expf(s - m);
    #pragma unroll
    for (int d = 32; d >= 1; d >>= 1) e += __shfl_xor(e, d, 64);
    float lse = m + __logf(e);

    float numer = __shfl(s, 0, 64);    // positive similarity (lane 0's s)

    if (lane == 0) {
        float loss = (lse - numer) * (1.0f / (float)BATCH);
        atomicAdd(out, loss);
    }
}

extern "C" void kernel_launch(void* const* d_in, const int* in_sizes, int n_in,
                              void* d_out, int out_size, void* d_ws, size_t ws_size,
                              hipStream_t stream) {
    const float* q   = (const float*)d_in[0];
    const float* r   = (const float*)d_in[1];
    const int*   pos = (const int*)d_in[2];
    const int*   neg = (const int*)d_in[3];
    float* out = (float*)d_out;

    // Timed replays don't re-zero d_out; we accumulate with atomics, so zero it.
    hipMemsetAsync(out, 0, sizeof(float), stream);

    dim3 block(256);
    dim3 grid(BATCH / 4);   // 4 waves per block, 1 wave per batch row
    infonce_kernel<<<grid, block, 0, stream>>>(q, r, pos, neg, out);
}

// Round 2
// 41.192 us; speedup vs baseline: 1.1095x; 1.1095x over previous
//
#include <hip/hip_runtime.h>

// InfoNCE loss, round 2: 4 lanes per candidate for coalescing + occupancy.
// Block = 256 threads = one batch row: 64 candidates x 4 lanes.
// Lane group (4c..4c+3) reads candidate c's 512B row as interleaved float4s,
// so each wave-level load instruction touches 16 contiguous 64B segments
// instead of 64 scattered 16B ones. Grid = 2048 blocks -> 32 waves/CU.

constexpr int BATCH = 2048;
constexpr int DIM   = 128;
constexpr int N_NEG = 63;
constexpr float TEMP_INV = 1.0f / 0.07f;
constexpr float EPSF = 1e-12f;

__global__ __launch_bounds__(256) void infonce_kernel(
    const float* __restrict__ q,    // [BATCH][DIM]
    const float* __restrict__ r,    // [VOCAB][DIM]
    const int*   __restrict__ pos,  // [BATCH]
    const int*   __restrict__ neg,  // [BATCH][N_NEG]
    float* __restrict__ out)        // [1]
{
    const int b   = blockIdx.x;          // one batch row per block
    const int tid = threadIdx.x;
    const int c   = tid >> 2;            // candidate 0..63 (0 = positive)
    const int t   = tid & 3;             // sub-lane within candidate

    int idx = (c == 0) ? pos[b] : neg[(size_t)b * N_NEG + (c - 1)];

    const float4* rrow = reinterpret_cast<const float4*>(r + (size_t)idx * DIM);
    const float4* qrow = reinterpret_cast<const float4*>(q + (size_t)b * DIM);

    float dot = 0.0f, rn = 0.0f, qn = 0.0f;
    #pragma unroll
    for (int j = 0; j < DIM / 16; ++j) {          // 8 iterations
        float4 rv = rrow[t + 4 * j];              // lanes 4c..4c+3 -> contiguous 64B
        float4 qv = qrow[t + 4 * j];              // same addr across the 16 groups -> L1 broadcast
        dot += qv.x * rv.x + qv.y * rv.y + qv.z * rv.z + qv.w * rv.w;
        rn  += rv.x * rv.x + rv.y * rv.y + rv.z * rv.z + rv.w * rv.w;
        qn  += qv.x * qv.x + qv.y * qv.y + qv.z * qv.z + qv.w * qv.w;
    }

    // reduce dot, rn, qn over the 4-lane candidate group
    #pragma unroll
    for (int d = 1; d <= 2; d <<= 1) {
        dot += __shfl_xor(dot, d, 64);
        rn  += __shfl_xor(rn,  d, 64);
        qn  += __shfl_xor(qn,  d, 64);
    }

    float qnorm = fmaxf(sqrtf(qn), EPSF);
    float rnorm = fmaxf(sqrtf(rn), EPSF);
    float s = dot / (qnorm * rnorm) * TEMP_INV;   // score for candidate c

    __shared__ float sv[64];
    if (t == 0) sv[c] = s;
    __syncthreads();

    // wave 0 does the 64-way logsumexp
    if (tid < 64) {
        float x = sv[tid];
        float m = x;
        #pragma unroll
        for (int d = 32; d >= 1; d >>= 1) m = fmaxf(m, __shfl_xor(m, d, 64));
        float e = __expf(x - m);
        #pragma unroll
        for (int d = 32; d >= 1; d >>= 1) e += __shfl_xor(e, d, 64);
        if (tid == 0) {
            float lse = m + __logf(e);
            float loss = (lse - sv[0]) * (1.0f / (float)BATCH);
            atomicAdd(out, loss);
        }
    }
}

extern "C" void kernel_launch(void* const* d_in, const int* in_sizes, int n_in,
                              void* d_out, int out_size, void* d_ws, size_t ws_size,
                              hipStream_t stream) {
    const float* q   = (const float*)d_in[0];
    const float* r   = (const float*)d_in[1];
    const int*   pos = (const int*)d_in[2];
    const int*   neg = (const int*)d_in[3];
    float* out = (float*)d_out;

    // Timed replays don't re-zero d_out; we accumulate with atomics, so zero it.
    hipMemsetAsync(out, 0, sizeof(float), stream);

    dim3 block(256);
    dim3 grid(BATCH);   // one batch row per block
    infonce_kernel<<<grid, block, 0, stream>>>(q, r, pos, neg, out);
}

// Round 3
// 18.202 us; speedup vs baseline: 2.5107x; 2.2630x over previous
//
#include <hip/hip_runtime.h>

// InfoNCE loss, round 3.
// - No atomics, no memset: kernel 1 writes per-row partial losses to d_ws,
//   kernel 2 (1 block) reduces 2048 -> out[0] with a plain store.
// - Loads restructured as explicit arrays (load loop, then compute loop) so
//   all 16 float4 loads per thread are in flight simultaneously.

constexpr int BATCH = 2048;
constexpr int DIM   = 128;
constexpr int N_NEG = 63;
constexpr float TEMP_INV = 1.0f / 0.07f;
constexpr float EPSF = 1e-12f;

__global__ __launch_bounds__(256) void infonce_partial(
    const float* __restrict__ q,       // [BATCH][DIM]
    const float* __restrict__ r,       // [VOCAB][DIM]
    const int*   __restrict__ pos,     // [BATCH]
    const int*   __restrict__ neg,     // [BATCH][N_NEG]
    float* __restrict__ partial)       // [BATCH]
{
    const int b   = blockIdx.x;          // one batch row per block
    const int tid = threadIdx.x;
    const int c   = tid >> 2;            // candidate 0..63 (0 = positive)
    const int t   = tid & 3;             // sub-lane within candidate

    int idx = (c == 0) ? pos[b] : neg[(size_t)b * N_NEG + (c - 1)];

    const float4* rrow = reinterpret_cast<const float4*>(r + (size_t)idx * DIM);
    const float4* qrow = reinterpret_cast<const float4*>(q + (size_t)b * DIM);

    // Load everything first (16 independent float4 loads), compute after.
    float4 rv[8], qv[8];
    #pragma unroll
    for (int j = 0; j < 8; ++j) rv[j] = rrow[t + 4 * j];
    #pragma unroll
    for (int j = 0; j < 8; ++j) qv[j] = qrow[t + 4 * j];

    float dot = 0.0f, rn = 0.0f, qn = 0.0f;
    #pragma unroll
    for (int j = 0; j < 8; ++j) {
        dot += qv[j].x * rv[j].x + qv[j].y * rv[j].y + qv[j].z * rv[j].z + qv[j].w * rv[j].w;
        rn  += rv[j].x * rv[j].x + rv[j].y * rv[j].y + rv[j].z * rv[j].z + rv[j].w * rv[j].w;
        qn  += qv[j].x * qv[j].x + qv[j].y * qv[j].y + qv[j].z * qv[j].z + qv[j].w * qv[j].w;
    }

    // reduce dot, rn, qn over the 4-lane candidate group
    #pragma unroll
    for (int d = 1; d <= 2; d <<= 1) {
        dot += __shfl_xor(dot, d, 64);
        rn  += __shfl_xor(rn,  d, 64);
        qn  += __shfl_xor(qn,  d, 64);
    }

    float qnorm = fmaxf(sqrtf(qn), EPSF);
    float rnorm = fmaxf(sqrtf(rn), EPSF);
    float s = dot / (qnorm * rnorm) * TEMP_INV;   // score for candidate c

    __shared__ float sv[64];
    if (t == 0) sv[c] = s;
    __syncthreads();

    // wave 0 does the 64-way logsumexp and stores the per-row partial
    if (tid < 64) {
        float x = sv[tid];
        float m = x;
        #pragma unroll
        for (int d = 32; d >= 1; d >>= 1) m = fmaxf(m, __shfl_xor(m, d, 64));
        float e = __expf(x - m);
        #pragma unroll
        for (int d = 32; d >= 1; d >>= 1) e += __shfl_xor(e, d, 64);
        if (tid == 0) {
            float lse = m + __logf(e);
            partial[b] = lse - sv[0];          // un-normalized per-row loss
        }
    }
}

__global__ __launch_bounds__(256) void infonce_reduce(
    const float* __restrict__ partial,   // [BATCH]
    float* __restrict__ out)             // [1]
{
    const int tid = threadIdx.x;
    float s = 0.0f;
    #pragma unroll
    for (int j = 0; j < BATCH / 256; ++j) s += partial[tid + 256 * j];

    #pragma unroll
    for (int d = 32; d >= 1; d >>= 1) s += __shfl_xor(s, d, 64);

    __shared__ float wsum[4];
    if ((tid & 63) == 0) wsum[tid >> 6] = s;
    __syncthreads();
    if (tid == 0)
        out[0] = (wsum[0] + wsum[1] + wsum[2] + wsum[3]) * (1.0f / (float)BATCH);
}

extern "C" void kernel_launch(void* const* d_in, const int* in_sizes, int n_in,
                              void* d_out, int out_size, void* d_ws, size_t ws_size,
                              hipStream_t stream) {
    const float* q   = (const float*)d_in[0];
    const float* r   = (const float*)d_in[1];
    const int*   pos = (const int*)d_in[2];
    const int*   neg = (const int*)d_in[3];
    float* out     = (float*)d_out;
    float* partial = (float*)d_ws;       // 2048 floats, fully rewritten each call

    infonce_partial<<<dim3(BATCH), dim3(256), 0, stream>>>(q, r, pos, neg, partial);
    infonce_reduce<<<dim3(1), dim3(256), 0, stream>>>(partial, out);
}

// Round 4
// 18.066 us; speedup vs baseline: 2.5297x; 1.0076x over previous
//
#include <hip/hip_runtime.h>

// InfoNCE loss, round 4.
// 512-thread blocks, one batch row per block: 64 candidates x 8 lanes.
// Per thread: 4 r-float4 + 4 q-float4 loads (all issued back-to-back),
// VGPR ~64 -> 8 waves/SIMD, full 32 waves/CU occupancy.
// Candidate group (8 lanes) covers 128B contiguous per wave instruction.

constexpr int BATCH = 2048;
constexpr int DIM   = 128;
constexpr int N_NEG = 63;
constexpr float TEMP_INV = 1.0f / 0.07f;
constexpr float EPSF = 1e-12f;

__global__ __launch_bounds__(512) void infonce_partial(
    const float* __restrict__ q,       // [BATCH][DIM]
    const float* __restrict__ r,       // [VOCAB][DIM]
    const int*   __restrict__ pos,     // [BATCH]
    const int*   __restrict__ neg,     // [BATCH][N_NEG]
    float* __restrict__ partial)       // [BATCH]
{
    const int b   = blockIdx.x;          // one batch row per block
    const int tid = threadIdx.x;         // 0..511
    const int c   = tid >> 3;            // candidate 0..63 (0 = positive)
    const int t   = tid & 7;             // sub-lane within candidate

    int idx = (c == 0) ? pos[b] : neg[(size_t)b * N_NEG + (c - 1)];

    const float4* rrow = reinterpret_cast<const float4*>(r + (size_t)idx * DIM);
    const float4* qrow = reinterpret_cast<const float4*>(q + (size_t)b * DIM);

    // Load everything first (8 independent float4 loads), compute after.
    float4 rv[4], qv[4];
    #pragma unroll
    for (int j = 0; j < 4; ++j) rv[j] = rrow[t + 8 * j];
    #pragma unroll
    for (int j = 0; j < 4; ++j) qv[j] = qrow[t + 8 * j];

    float dot = 0.0f, rn = 0.0f, qn = 0.0f;
    #pragma unroll
    for (int j = 0; j < 4; ++j) {
        dot += qv[j].x * rv[j].x + qv[j].y * rv[j].y + qv[j].z * rv[j].z + qv[j].w * rv[j].w;
        rn  += rv[j].x * rv[j].x + rv[j].y * rv[j].y + rv[j].z * rv[j].z + rv[j].w * rv[j].w;
        qn  += qv[j].x * qv[j].x + qv[j].y * qv[j].y + qv[j].z * qv[j].z + qv[j].w * qv[j].w;
    }

    // reduce dot, rn, qn over the 8-lane candidate group (aligned within wave)
    #pragma unroll
    for (int d = 1; d <= 4; d <<= 1) {
        dot += __shfl_xor(dot, d, 64);
        rn  += __shfl_xor(rn,  d, 64);
        qn  += __shfl_xor(qn,  d, 64);
    }

    float qnorm = fmaxf(sqrtf(qn), EPSF);
    float rnorm = fmaxf(sqrtf(rn), EPSF);
    float s = dot / (qnorm * rnorm) * TEMP_INV;   // score for candidate c

    __shared__ float sv[64];
    if (t == 0) sv[c] = s;
    __syncthreads();

    // wave 0 does the 64-way logsumexp and stores the per-row partial
    if (tid < 64) {
        float x = sv[tid];
        float m = x;
        #pragma unroll
        for (int d = 32; d >= 1; d >>= 1) m = fmaxf(m, __shfl_xor(m, d, 64));
        float e = __expf(x - m);
        #pragma unroll
        for (int d = 32; d >= 1; d >>= 1) e += __shfl_xor(e, d, 64);
        if (tid == 0) {
            float lse = m + __logf(e);
            partial[b] = lse - sv[0];          // un-normalized per-row loss
        }
    }
}

__global__ __launch_bounds__(256) void infonce_reduce(
    const float* __restrict__ partial,   // [BATCH]
    float* __restrict__ out)             // [1]
{
    const int tid = threadIdx.x;
    float s = 0.0f;
    #pragma unroll
    for (int j = 0; j < BATCH / 256; ++j) s += partial[tid + 256 * j];

    #pragma unroll
    for (int d = 32; d >= 1; d >>= 1) s += __shfl_xor(s, d, 64);

    __shared__ float wsum[4];
    if ((tid & 63) == 0) wsum[tid >> 6] = s;
    __syncthreads();
    if (tid == 0)
        out[0] = (wsum[0] + wsum[1] + wsum[2] + wsum[3]) * (1.0f / (float)BATCH);
}

extern "C" void kernel_launch(void* const* d_in, const int* in_sizes, int n_in,
                              void* d_out, int out_size, void* d_ws, size_t ws_size,
                              hipStream_t stream) {
    const float* q   = (const float*)d_in[0];
    const float* r   = (const float*)d_in[1];
    const int*   pos = (const int*)d_in[2];
    const int*   neg = (const int*)d_in[3];
    float* out     = (float*)d_out;
    float* partial = (float*)d_ws;       // 2048 floats, fully rewritten each call

    infonce_partial<<<dim3(BATCH), dim3(512), 0, stream>>>(q, r, pos, neg, partial);
    infonce_reduce<<<dim3(1), dim3(256), 0, stream>>>(partial, out);
}

// Round 6
// 16.805 us; speedup vs baseline: 2.7195x; 1.0750x over previous
//
#include <hip/hip_runtime.h>

// InfoNCE loss, round 5b (compile fix).
// Non-temporal gather loads via ext_vector_type(4) (builtin rejects
// HIP_vector_type). Reduce kernel: contiguous float4 loads.

constexpr int BATCH = 2048;
constexpr int DIM   = 128;
constexpr int N_NEG = 63;
constexpr float TEMP_INV = 1.0f / 0.07f;
constexpr float EPSF = 1e-12f;

typedef float v4f __attribute__((ext_vector_type(4)));

__global__ __launch_bounds__(512) void infonce_partial(
    const float* __restrict__ q,       // [BATCH][DIM]
    const float* __restrict__ r,       // [VOCAB][DIM]
    const int*   __restrict__ pos,     // [BATCH]
    const int*   __restrict__ neg,     // [BATCH][N_NEG]
    float* __restrict__ partial)       // [BATCH]
{
    const int b   = blockIdx.x;          // one batch row per block
    const int tid = threadIdx.x;         // 0..511
    const int c   = tid >> 3;            // candidate 0..63 (0 = positive)
    const int t   = tid & 7;             // sub-lane within candidate

    int idx = (c == 0) ? pos[b] : neg[(size_t)b * N_NEG + (c - 1)];

    const v4f* rrow = reinterpret_cast<const v4f*>(r + (size_t)idx * DIM);
    const v4f* qrow = reinterpret_cast<const v4f*>(q + (size_t)b * DIM);

    // Load everything first (8 independent 16B loads), compute after.
    // r-rows: non-temporal (bypass L1 allocate; no reuse at this level).
    v4f rv[4], qv[4];
    #pragma unroll
    for (int j = 0; j < 4; ++j) rv[j] = __builtin_nontemporal_load(&rrow[t + 8 * j]);
    #pragma unroll
    for (int j = 0; j < 4; ++j) qv[j] = qrow[t + 8 * j];

    float dot = 0.0f, rn = 0.0f, qn = 0.0f;
    #pragma unroll
    for (int j = 0; j < 4; ++j) {
        dot += qv[j].x * rv[j].x + qv[j].y * rv[j].y + qv[j].z * rv[j].z + qv[j].w * rv[j].w;
        rn  += rv[j].x * rv[j].x + rv[j].y * rv[j].y + rv[j].z * rv[j].z + rv[j].w * rv[j].w;
        qn  += qv[j].x * qv[j].x + qv[j].y * qv[j].y + qv[j].z * qv[j].z + qv[j].w * qv[j].w;
    }

    // reduce dot, rn, qn over the 8-lane candidate group (aligned within wave)
    #pragma unroll
    for (int d = 1; d <= 4; d <<= 1) {
        dot += __shfl_xor(dot, d, 64);
        rn  += __shfl_xor(rn,  d, 64);
        qn  += __shfl_xor(qn,  d, 64);
    }

    float qnorm = fmaxf(sqrtf(qn), EPSF);
    float rnorm = fmaxf(sqrtf(rn), EPSF);
    float s = dot / (qnorm * rnorm) * TEMP_INV;   // score for candidate c

    __shared__ float sv[64];
    if (t == 0) sv[c] = s;
    __syncthreads();

    // wave 0 does the 64-way logsumexp and stores the per-row partial
    if (tid < 64) {
        float x = sv[tid];
        float m = x;
        #pragma unroll
        for (int d = 32; d >= 1; d >>= 1) m = fmaxf(m, __shfl_xor(m, d, 64));
        float e = __expf(x - m);
        #pragma unroll
        for (int d = 32; d >= 1; d >>= 1) e += __shfl_xor(e, d, 64);
        if (tid == 0) {
            float lse = m + __logf(e);
            partial[b] = lse - sv[0];          // un-normalized per-row loss
        }
    }
}

__global__ __launch_bounds__(512) void infonce_reduce(
    const float* __restrict__ partial,   // [BATCH]
    float* __restrict__ out)             // [1]
{
    const int tid = threadIdx.x;         // 0..511
    // 2048 floats = 512 float4, one contiguous float4 per thread
    v4f v = reinterpret_cast<const v4f*>(partial)[tid];
    float s = v.x + v.y + v.z + v.w;

    #pragma unroll
    for (int d = 32; d >= 1; d >>= 1) s += __shfl_xor(s, d, 64);

    __shared__ float wsum[8];
    if ((tid & 63) == 0) wsum[tid >> 6] = s;
    __syncthreads();
    if (tid == 0) {
        float tot = 0.0f;
        #pragma unroll
        for (int w = 0; w < 8; ++w) tot += wsum[w];
        out[0] = tot * (1.0f / (float)BATCH);
    }
}

extern "C" void kernel_launch(void* const* d_in, const int* in_sizes, int n_in,
                              void* d_out, int out_size, void* d_ws, size_t ws_size,
                              hipStream_t stream) {
    const float* q   = (const float*)d_in[0];
    const float* r   = (const float*)d_in[1];
    const int*   pos = (const int*)d_in[2];
    const int*   neg = (const int*)d_in[3];
    float* out     = (float*)d_out;
    float* partial = (float*)d_ws;       // 2048 floats, fully rewritten each call

    infonce_partial<<<dim3(BATCH), dim3(512), 0, stream>>>(q, r, pos, neg, partial);
    infonce_reduce<<<dim3(1), dim3(512), 0, stream>>>(partial, out);
}